// Round 6
// baseline (299.876 us; speedup 1.0000x reference)
//
#include <hip/hip_runtime.h>
#include <math.h>
#include <float.h>

#define HW 4096
#define CHW 262144
#define NTOK 65536
#define NELEM 4194304

// ws float offsets
#define WS_LOSS 0        // 512 floats
#define WS_STD  512      // 64
#define WS_EE   576      // 1024
#define WS_ETG  1600     // 65536 : codebook transposed [64 c][1024 k]
#define WS_DONE 67136    // 1 int

// ---------------- k_pre: blocks 0..63 = per-channel std, 64..79 = transpose ----------------
__global__ __launch_bounds__(1024) void k_pre(const float* __restrict__ z,
                                              const float* __restrict__ emb,
                                              float* __restrict__ stdv,
                                              float* __restrict__ etg,
                                              float* __restrict__ eeg,
                                              int* __restrict__ done) {
  __shared__ double rs[16], rs2[16];
  __shared__ float T[64][65];
  int tid = threadIdx.x;
  int blk = blockIdx.x;
  if (blk == 0 && tid == 0) *done = 0;   // re-init every launch (ws is poisoned)
  if (blk < 64) {
    // per-channel std (ddof=1) — bit-identical to validated rounds
    int c = blk;
    double s = 0.0, s2 = 0.0;
    const float* base = z + c * HW;
    #pragma unroll 4
    for (int jj = 0; jj < 16; ++jj) {
      int f = tid + (jj << 10);
      int b = f >> 10, off4 = f & 1023;
      float4 v = *(const float4*)(base + (size_t)b * CHW + (off4 << 2));
      s  += (double)v.x + (double)v.y + (double)v.z + (double)v.w;
      s2 += (double)v.x * v.x + (double)v.y * v.y + (double)v.z * v.z + (double)v.w * v.w;
    }
    for (int o = 32; o > 0; o >>= 1) {
      s += __shfl_down(s, o, 64);
      s2 += __shfl_down(s2, o, 64);
    }
    int wv = tid >> 6, ln = tid & 63;
    if (ln == 0) { rs[wv] = s; rs2[wv] = s2; }
    __syncthreads();
    if (tid == 0) {
      double S = 0.0, S2 = 0.0;
      #pragma unroll
      for (int w = 0; w < 16; ++w) { S += rs[w]; S2 += rs2[w]; }
      const double N = (double)NTOK;
      double var = (S2 - S * S / N) / (N - 1.0);
      float sd = (float)sqrt(var);
      stdv[c] = fmaxf(sd, 1e-5f);
    }
  } else {
    // transpose 64 codebook rows to [c][k] + row norms (bit-identical norms)
    int k0 = (blk - 64) << 6;
    {
      int code = tid >> 4, c4 = tid & 15;
      float4 v = *(const float4*)(emb + (size_t)((k0 + code) << 6) + (c4 << 2));
      T[code][(c4 << 2) + 0] = v.x;
      T[code][(c4 << 2) + 1] = v.y;
      T[code][(c4 << 2) + 2] = v.z;
      T[code][(c4 << 2) + 3] = v.w;
    }
    __syncthreads();
    {
      int c = tid >> 4, k4 = tid & 15;
      float4 v = make_float4(T[(k4 << 2) + 0][c], T[(k4 << 2) + 1][c],
                             T[(k4 << 2) + 2][c], T[(k4 << 2) + 3][c]);
      *(float4*)(etg + c * 1024 + k0 + (k4 << 2)) = v;
    }
    if (tid < 64) {
      const float* er = emb + (size_t)((k0 + tid) << 6);
      float s = 0.f;
      #pragma unroll
      for (int c = 0; c < 64; ++c) s = fmaf(er[c], er[c], s);
      eeg[k0 + tid] = s;
    }
  }
}

// ---------------- main kernel: z from LDS, codes from VMEM, 8x8 acc ----------------
// Block = 128 tokens, 4 waves as 2x2 (token-half wt x code-half wc). Lane:
// tg=lane>>3 (8-token group), cg=lane&7 (8-code group). Per c-step: 2 ds_read_b128
// (z, broadcast across cg) + 2 global dwordx4 (codes from L1/L2-resident etg,
// broadcast across tg) feed 64 FMAs. DS pipe ~98k cyc/CU, VMEM ~65k, VALU ~139k
// -> VALU-bound. Dot order / distance expr / tie-breaks bit-identical.
#define STEP8(i, zc) \
  acc0[i].x = fmaf(zc, ea.x, acc0[i].x); \
  acc0[i].y = fmaf(zc, ea.y, acc0[i].y); \
  acc0[i].z = fmaf(zc, ea.z, acc0[i].z); \
  acc0[i].w = fmaf(zc, ea.w, acc0[i].w); \
  acc1[i].x = fmaf(zc, eb.x, acc1[i].x); \
  acc1[i].y = fmaf(zc, eb.y, acc1[i].y); \
  acc1[i].z = fmaf(zc, eb.z, acc1[i].z); \
  acc1[i].w = fmaf(zc, eb.w, acc1[i].w);

__global__ __launch_bounds__(256, 3) void k_vq(
    const float* __restrict__ z_e, const float* __restrict__ emb,
    const float* __restrict__ stdv, const float* __restrict__ eeg,
    const float* __restrict__ etg,
    float* __restrict__ out_zq, float* __restrict__ out_idx,
    float* __restrict__ loss_part, int* __restrict__ done,
    float* __restrict__ out_scalars) {
  __shared__ float zt[64 * 128];   // 32 KB [c][tok]
  __shared__ float zzt[128];
  __shared__ float sstd[64];
  __shared__ float rbd[2][128];
  __shared__ int   rbk[2][128];
  __shared__ int   skf[128];
  __shared__ float sred[4];
  __shared__ int   hist[1024];
  __shared__ int   lastFlag;
  __shared__ double rl[4], rh[4];

  int tid = threadIdx.x;
  int lane = tid & 63;
  int wv = tid >> 6;
  int blk = blockIdx.x;           // 512 blocks
  int b = blk >> 5;
  int s0 = (blk & 31) << 7;       // 128 contiguous spatial positions

  if (tid < 64) sstd[tid] = stdv[tid];
  __syncthreads();

  // stage zt (normalized, IEEE div — bit-identical)
  const float* zbase = z_e + (size_t)b * CHW + s0;
  #pragma unroll
  for (int jj = 0; jj < 8; ++jj) {
    int f = tid + (jj << 8);
    int c = f >> 5, t4 = f & 31;
    float4 v = *(const float4*)(zbase + (size_t)c * HW + (t4 << 2));
    float sd = sstd[c];
    v.x /= sd; v.y /= sd; v.z /= sd; v.w /= sd;
    *(float4*)&zt[(c << 7) + (t4 << 2)] = v;
  }
  __syncthreads();

  // zz (ascending-c fmaf, bit-identical)
  if (tid < 128) {
    float a = 0.f;
    #pragma unroll
    for (int c = 0; c < 64; ++c) { float v = zt[(c << 7) + tid]; a = fmaf(v, v, a); }
    zzt[tid] = a;
  }
  __syncthreads();

  int tg = lane >> 3, cg = lane & 7;
  int wt = wv >> 1, wc = wv & 1;
  int tbase = wt * 64 + tg * 8;         // this lane's 8 tokens
  const float4* zp = (const float4*)&zt[tbase];

  float zzr[8];
  #pragma unroll
  for (int ii = 0; ii < 8; ++ii) zzr[ii] = zzt[tbase + ii];

  float bd[8]; int bk[8];
  #pragma unroll
  for (int ii = 0; ii < 8; ++ii) { bd[ii] = FLT_MAX; bk[ii] = 0; }

  for (int pass = 0; pass < 8; ++pass) {
    int kk = (pass << 7) + (wc << 6) + (cg << 3);   // lane's 8 contiguous codes
    const float* ep = etg + kk;

    float4 acc0[8], acc1[8];
    #pragma unroll
    for (int ii = 0; ii < 8; ++ii) {
      acc0[ii] = make_float4(0.f, 0.f, 0.f, 0.f);
      acc1[ii] = make_float4(0.f, 0.f, 0.f, 0.f);
    }

    #pragma unroll 4
    for (int c = 0; c < 64; ++c) {
      float4 ea = *(const float4*)ep;          // codes kk..kk+3, channel c
      float4 eb = *(const float4*)(ep + 4);    // codes kk+4..kk+7
      float4 za = zp[c << 5];
      float4 zb = zp[(c << 5) + 1];
      STEP8(0, za.x) STEP8(1, za.y) STEP8(2, za.z) STEP8(3, za.w)
      STEP8(4, zb.x) STEP8(5, zb.y) STEP8(6, zb.z) STEP8(7, zb.w)
      ep += 1024;
    }

    float4 eea = *(const float4*)(eeg + kk);
    float4 eeb = *(const float4*)(eeg + kk + 4);
    float eev[8] = {eea.x, eea.y, eea.z, eea.w, eeb.x, eeb.y, eeb.z, eeb.w};
    #pragma unroll
    for (int ii = 0; ii < 8; ++ii) {
      float z2 = zzr[ii];
      float av[8] = {acc0[ii].x, acc0[ii].y, acc0[ii].z, acc0[ii].w,
                     acc1[ii].x, acc1[ii].y, acc1[ii].z, acc1[ii].w};
      #pragma unroll
      for (int jj = 0; jj < 8; ++jj) {       // ascending k within lane
        float dd = (z2 - 2.0f * av[jj]) + eev[jj];
        if (dd < bd[ii]) { bd[ii] = dd; bk[ii] = kk + jj; }
      }
    }
  }

  // reduce across the 8 code-groups (lane bits 0..2); tie -> smaller k
  #pragma unroll
  for (int m = 1; m <= 4; m <<= 1) {
    #pragma unroll
    for (int ii = 0; ii < 8; ++ii) {
      float od = __shfl_xor(bd[ii], m, 64);
      int   ok = __shfl_xor(bk[ii], m, 64);
      if (od < bd[ii] || (od == bd[ii] && ok < bk[ii])) { bd[ii] = od; bk[ii] = ok; }
    }
  }
  if (cg == 0) {
    #pragma unroll
    for (int ii = 0; ii < 8; ++ii) { rbd[wc][tbase + ii] = bd[ii]; rbk[wc][tbase + ii] = bk[ii]; }
  }
  __syncthreads();

  if (tid < 128) {
    float d0 = rbd[0][tid]; int k0 = rbk[0][tid];
    float d1 = rbd[1][tid]; int k1 = rbk[1][tid];
    int kb2 = (d1 < d0 || (d1 == d0 && k1 < k0)) ? k1 : k0;
    skf[tid] = kb2;
    out_idx[(blk << 7) + tid] = (float)kb2;
  }
  __syncthreads();

  // epilogue: z from LDS (bit-same), e gathered from emb, coalesced stores
  {
    int t = tid & 127;
    int ch = tid >> 7;
    int kq = skf[t];
    const float* eq = emb + (size_t)(kq << 6) + (ch << 5);
    float lsum = 0.f;
    float* ob = out_zq + (size_t)b * CHW + s0 + t;
    #pragma unroll
    for (int jj = 0; jj < 32; ++jj) {
      int c = (ch << 5) + jj;
      float zv = zt[(c << 7) + t];
      float e = eq[jj];
      float df = zv - e;
      lsum = fmaf(df, df, lsum);
      ob[(size_t)c * HW] = zv + (e - zv);
    }
    for (int o = 32; o > 0; o >>= 1) lsum += __shfl_down(lsum, o, 64);
    if (lane == 0) sred[wv] = lsum;
  }
  __syncthreads();

  // completion counter: last block finalizes (split-k fixup pattern)
  if (tid == 0) {
    loss_part[blk] = sred[0] + sred[1] + sred[2] + sred[3];
    __threadfence();                       // publish idx + loss device-wide
    int prev = atomicAdd(done, 1);
    lastFlag = (prev == 511);
  }
  __syncthreads();
  if (!lastFlag) return;

  // ---- finalize (one block): histogram + vq_loss + perplexity ----
  #pragma unroll
  for (int jj = 0; jj < 4; ++jj) hist[tid + (jj << 8)] = 0;
  __syncthreads();
  {
    const float2* idx2 = (const float2*)out_idx;   // 8B-aligned base
    for (int i = tid; i < NTOK / 2; i += 256) {
      float2 v = idx2[i];
      atomicAdd(&hist[(int)v.x], 1);
      atomicAdd(&hist[(int)v.y], 1);
    }
  }
  __syncthreads();
  double ls = (double)loss_part[tid] + (double)loss_part[tid + 256];
  double hs = 0.0;
  #pragma unroll
  for (int jj = 0; jj < 4; ++jj) {
    float p = (float)hist[tid + (jj << 8)] * (1.0f / 65536.0f);
    float lg = logf(fmaxf(p, 1e-10f));
    hs += (double)(p * lg);
  }
  for (int o = 32; o > 0; o >>= 1) {
    ls += __shfl_down(ls, o, 64);
    hs += __shfl_down(hs, o, 64);
  }
  if (lane == 0) { rl[wv] = ls; rh[wv] = hs; }
  __syncthreads();
  if (tid == 0) {
    double L = rl[0] + rl[1] + rl[2] + rl[3];
    double Hn = rh[0] + rh[1] + rh[2] + rh[3];
    float m = (float)(L / (double)NELEM);
    out_scalars[0] = 0.25f * m + m;
    out_scalars[1] = expf((float)(-Hn));
  }
}

extern "C" void kernel_launch(void* const* d_in, const int* in_sizes, int n_in,
                              void* d_out, int out_size, void* d_ws, size_t ws_size,
                              hipStream_t stream) {
  const float* z_e = (const float*)d_in[0];
  const float* emb = (const float*)d_in[1];
  float* ws = (float*)d_ws;
  float* loss_part = ws + WS_LOSS;
  float* stdv = ws + WS_STD;
  float* eeg = ws + WS_EE;
  float* etg = ws + WS_ETG;
  int* done = (int*)(ws + WS_DONE);    // total ws use ~263 KB

  float* out = (float*)d_out;
  float* out_zq = out;                  // 4194304
  float* out_scalars = out + NELEM;     // vq_loss, perplexity
  float* out_idx = out + NELEM + 2;     // 65536 indices as float

  k_pre<<<80, 1024, 0, stream>>>(z_e, emb, stdv, etg, eeg, done);
  k_vq<<<512, 256, 0, stream>>>(z_e, emb, stdv, eeg, etg, out_zq, out_idx,
                                loss_part, done, out_scalars);
}